// Round 1
// baseline (1341.518 us; speedup 1.0000x reference)
//
#include <hip/hip_runtime.h>

#define Bn 4
#define Nn 4096
#define En 131072
#define Hn 128
#define Fn 140
#define FPn 160

typedef __bf16 bf16v8 __attribute__((ext_vector_type(8)));
typedef float f32v4 __attribute__((ext_vector_type(4)));
typedef unsigned short u16;
typedef unsigned int u32;

__device__ __forceinline__ u16 f2bf(float f) {
  union { float f; u32 u; } v; v.f = f;
  u32 r = v.u + 0x7fffu + ((v.u >> 16) & 1u);
  return (u16)(r >> 16);
}

__device__ __forceinline__ float sigm(float x) { return 1.0f / (1.0f + __expf(-x)); }

__device__ __forceinline__ void zero8(f32v4* acc) {
  f32v4 z = {0.f, 0.f, 0.f, 0.f};
#pragma unroll
  for (int c = 0; c < 8; ++c) acc[c] = z;
}

// acc[c] += X[16][K] (LDS tile, row stride ldx) @ W[K][128], where Wt[n][k] = W[k][n]
// MFMA 16x16x32 bf16 layouts (HW-verified m89/m91/m120):
//   A[m=lane&15][k=quad*8+j], B[k=quad*8+j][n=lane&15], C/D row=quad*4+v col=lane&15
__device__ __forceinline__ void wave_gemm(const u16* Xlds, int ldx,
                                          const u16* __restrict__ Wt, int kpad, int K,
                                          f32v4* acc, int lane) {
  const int m = lane & 15, quad = lane >> 4;
  const u16* xp = Xlds + m * ldx + quad * 8;
  const u16* wp = Wt + m * kpad + quad * 8;
  for (int k0 = 0; k0 < K; k0 += 32) {
    bf16v8 a = *(const bf16v8*)(xp + k0);
#pragma unroll
    for (int c = 0; c < 8; ++c) {
      bf16v8 b = *(const bf16v8*)(wp + c * 16 * kpad + k0);
      acc[c] = __builtin_amdgcn_mfma_f32_16x16x32_bf16(a, b, acc[c], 0, 0, 0);
    }
  }
}

template <int ACT>  // 0=tanh, 1=relu
__device__ __forceinline__ void act_store(const f32v4* acc, const float* __restrict__ bias,
                                          u16* dst, int ldd, int lane) {
  const int m = lane & 15, quad = lane >> 4;
#pragma unroll
  for (int c = 0; c < 8; ++c) {
    const int col = c * 16 + m;
    const float bv = bias[col];
#pragma unroll
    for (int v = 0; v < 4; ++v) {
      float x = acc[c][v] + bv;
      x = (ACT == 0) ? tanhf(x) : fmaxf(x, 0.f);
      dst[(quad * 4 + v) * ldd + col] = f2bf(x);
    }
  }
}

// ---------------- prep kernels ----------------

struct WD { const float* src; u16* dst; int K; int Kpad; };
struct WT { WD d[15]; };

__global__ __launch_bounds__(256) void wconv_kernel(WT t) {
  WD w = t.d[blockIdx.x];
  const int total = 128 * w.Kpad;
  for (int i = threadIdx.x; i < total; i += 256) {
    int n = i / w.Kpad, k = i - n * w.Kpad;
    float v = (k < w.K) ? w.src[(size_t)k * 128 + n] : 0.f;
    w.dst[i] = f2bf(v);
  }
}

__global__ __launch_bounds__(256) void conv_kernel(const float* __restrict__ a,
                                                   const float* __restrict__ b,
                                                   u16* __restrict__ ab,
                                                   u16* __restrict__ bb) {
  const int n4 = (Bn * Nn * Hn) / 4;  // float4 count per array
  int idx = blockIdx.x * 256 + threadIdx.x;
  const float* src; u16* dst;
  if (idx < n4) { src = a; dst = ab; }
  else { idx -= n4; src = b; dst = bb; }
  float4 f = ((const float4*)src)[idx];
  uint2 p;
  p.x = (u32)f2bf(f.x) | ((u32)f2bf(f.y) << 16);
  p.y = (u32)f2bf(f.z) | ((u32)f2bf(f.w) << 16);
  ((uint2*)dst)[idx] = p;
}

__global__ __launch_bounds__(256) void count_kernel(const int* __restrict__ recv,
                                                    float* __restrict__ cnt) {
  int e = blockIdx.x * 256 + threadIdx.x;
  if (e < En) atomicAdd(&cnt[recv[e]], 1.0f);
}

// ---------------- msg edge kernel: gather + 2-layer tanh MLP + scatter ----------------

__global__ __launch_bounds__(256) void msg_kernel(
    const u16* __restrict__ hbf, const int* __restrict__ recv, const int* __restrict__ send,
    const u16* __restrict__ w1t, const float* __restrict__ b1,
    const u16* __restrict__ w2t, const float* __restrict__ b2,
    float* __restrict__ hidden_sum) {
  __shared__ u16 sX[4][16][264];   // 256 cols + 8 pad
  __shared__ u16 sX1[4][16][136];  // 128 cols + 8 pad
  const int tid = threadIdx.x, wave = tid >> 6, lane = tid & 63;
  const int row0 = blockIdx.x * 64 + wave * 16;
  const int half = lane >> 5, c4 = (lane & 31) * 4;
  // gather: row = b*E + e ; cols [0,128) = hidden[b,recv[e]], [128,256) = hidden[b,send[e]]
  for (int i = 0; i < 16; ++i) {
    int r = row0 + i;
    int e = r & (En - 1);
    int b = r >> 17;
    int node = half ? send[e] : recv[e];
    const u16* src = hbf + (((size_t)(b * Nn + node)) << 7) + c4;
    *(uint2*)&sX[wave][i][half * 128 + c4] = *(const uint2*)src;
  }
  __syncthreads();
  f32v4 acc[8];
  zero8(acc);
  wave_gemm(&sX[wave][0][0], 264, w1t, 256, 256, acc, lane);
  act_store<0>(acc, b1, &sX1[wave][0][0], 136, lane);
  __syncthreads();
  zero8(acc);
  wave_gemm(&sX1[wave][0][0], 136, w2t, 128, 128, acc, lane);
  const int m = lane & 15, quad = lane >> 4;
#pragma unroll
  for (int v = 0; v < 4; ++v) {
    int r = row0 + quad * 4 + v;
    int e = r & (En - 1);
    int b = r >> 17;
    int node = recv[e];
    float* dst = hidden_sum + (((size_t)(b * Nn + node)) << 7);
#pragma unroll
    for (int c = 0; c < 8; ++c) {
      int col = c * 16 + m;
      atomicAdd(dst + col, tanhf(acc[c][v] + b2[col]));
    }
  }
}

// ---------------- pm edge kernel: edge_attr relu MLP + scatter ----------------

__global__ __launch_bounds__(256) void pm_kernel(
    const float* __restrict__ ea, const int* __restrict__ recv,
    const u16* __restrict__ w1t, const float* __restrict__ b1,
    const u16* __restrict__ w2t, const float* __restrict__ b2,
    float* __restrict__ present_sum) {
  __shared__ u16 sX[4][16][168];   // 160 cols + 8 pad
  __shared__ u16 sX1[4][16][136];
  const int tid = threadIdx.x, wave = tid >> 6, lane = tid & 63;
  const int row0 = blockIdx.x * 64 + wave * 16;
  const int c4 = lane * 4;
  for (int i = 0; i < 16; ++i) {
    size_t r = (size_t)row0 + i;
    if (c4 < Fn) {  // c4 <= 136: full float4 in-bounds (140 = 35*4)
      float4 f = *(const float4*)(ea + r * Fn + c4);
      uint2 p;
      p.x = (u32)f2bf(f.x) | ((u32)f2bf(f.y) << 16);
      p.y = (u32)f2bf(f.z) | ((u32)f2bf(f.w) << 16);
      *(uint2*)&sX[wave][i][c4] = p;
    } else if (c4 < FPn) {  // zero-pad cols 140..159
      uint2 z; z.x = 0u; z.y = 0u;
      *(uint2*)&sX[wave][i][c4] = z;
    }
  }
  __syncthreads();
  f32v4 acc[8];
  zero8(acc);
  wave_gemm(&sX[wave][0][0], 168, w1t, FPn, FPn, acc, lane);
  act_store<1>(acc, b1, &sX1[wave][0][0], 136, lane);
  __syncthreads();
  zero8(acc);
  wave_gemm(&sX1[wave][0][0], 136, w2t, 128, 128, acc, lane);
  const int m = lane & 15, quad = lane >> 4;
#pragma unroll
  for (int v = 0; v < 4; ++v) {
    int r = row0 + quad * 4 + v;
    int e = r & (En - 1);
    int b = r >> 17;
    int node = recv[e];
    float* dst = present_sum + (((size_t)(b * Nn + node)) << 7);
#pragma unroll
    for (int c = 0; c < 8; ++c) {
      int col = c * 16 + m;
      atomicAdd(dst + col, fmaxf(acc[c][v] + b2[col], 0.f));
    }
  }
}

// ---------------- node kernel: res MLP + GRU + out MLP ----------------

__global__ __launch_bounds__(256) void node_kernel(
    const u16* __restrict__ inbf, const float* __restrict__ hidden,
    const float* __restrict__ hidden_sum, const float* __restrict__ present_sum,
    const float* __restrict__ cnt,
    const u16* __restrict__ rw1, const float* __restrict__ rb1,
    const u16* __restrict__ rw2, const float* __restrict__ rb2,
    const u16* __restrict__ irw, const float* __restrict__ irb,
    const u16* __restrict__ iiw, const float* __restrict__ iib,
    const u16* __restrict__ inw, const float* __restrict__ inb,
    const u16* __restrict__ hrw, const u16* __restrict__ hiw, const u16* __restrict__ hhw,
    const u16* __restrict__ o1w, const float* __restrict__ o1b,
    const u16* __restrict__ o2w, const float* __restrict__ o2b,
    const u16* __restrict__ o3w, const float* __restrict__ o3b,
    float* __restrict__ pred, float* __restrict__ new_hidden) {
  __shared__ u16 sA[4][16][136], sB[4][16][136], sC[4][16][136];
  const int tid = threadIdx.x, wave = tid >> 6, lane = tid & 63;
  const int row0 = blockIdx.x * 64 + wave * 16;  // row = b*N + n
  const int m = lane & 15, quad = lane >> 4;
  const int half = lane >> 5, c4 = (lane & 31) * 4;
  // stage inputs (bf16) rows
  for (int i = 0; i < 8; ++i) {
    int r = row0 + i * 2 + half;
    *(uint2*)&sA[wave][i * 2 + half][c4] = *(const uint2*)(inbf + ((size_t)r << 7) + c4);
  }
  __syncthreads();
  f32v4 acc[8];
  // res layer 1
  zero8(acc);
  wave_gemm(&sA[wave][0][0], 136, rw1, 128, 128, acc, lane);
  act_store<1>(acc, rb1, &sB[wave][0][0], 136, lane);
  __syncthreads();
  // res layer 2 -> P = res + present_mean (into sA), Hm = hidden_mean (into sB)
  zero8(acc);
  wave_gemm(&sB[wave][0][0], 136, rw2, 128, 128, acc, lane);
  __syncthreads();
#pragma unroll
  for (int v = 0; v < 4; ++v) {
    int r = row0 + quad * 4 + v;
    float ic = 1.f / fmaxf(cnt[r & (Nn - 1)], 1.f);
    const float* ps = present_sum + ((size_t)r << 7);
    const float* hs = hidden_sum + ((size_t)r << 7);
#pragma unroll
    for (int c = 0; c < 8; ++c) {
      int col = c * 16 + m;
      float res = fmaxf(acc[c][v] + rb2[col], 0.f);
      sA[wave][quad * 4 + v][col] = f2bf(res + ps[col] * ic);
      sB[wave][quad * 4 + v][col] = f2bf(hs[col] * ic);
    }
  }
  __syncthreads();
  // r gate
  float rg[8][4];
  zero8(acc);
  wave_gemm(&sA[wave][0][0], 136, irw, 128, 128, acc, lane);
  wave_gemm(&sB[wave][0][0], 136, hrw, 128, 128, acc, lane);
#pragma unroll
  for (int c = 0; c < 8; ++c) {
    int col = c * 16 + m;
#pragma unroll
    for (int v = 0; v < 4; ++v) rg[c][v] = sigm(acc[c][v] + irb[col]);
  }
  // n = tanh(P@in_w + in_b + r * (Hm@hh_w))  (reuse rg[] to hold n)
  f32v4 acc2[8];
  zero8(acc);
  wave_gemm(&sA[wave][0][0], 136, inw, 128, 128, acc, lane);
  zero8(acc2);
  wave_gemm(&sB[wave][0][0], 136, hhw, 128, 128, acc2, lane);
#pragma unroll
  for (int c = 0; c < 8; ++c) {
    int col = c * 16 + m;
#pragma unroll
    for (int v = 0; v < 4; ++v)
      rg[c][v] = tanhf(acc[c][v] + inb[col] + rg[c][v] * acc2[c][v]);
  }
  // i gate + new_hidden
  zero8(acc);
  wave_gemm(&sA[wave][0][0], 136, iiw, 128, 128, acc, lane);
  wave_gemm(&sB[wave][0][0], 136, hiw, 128, 128, acc, lane);
  __syncthreads();
#pragma unroll
  for (int v = 0; v < 4; ++v) {
    int r = row0 + quad * 4 + v;
    size_t ro = (size_t)r << 7;
#pragma unroll
    for (int c = 0; c < 8; ++c) {
      int col = c * 16 + m;
      float ig = sigm(acc[c][v] + iib[col]);
      float h = hidden[ro + col];
      float nh = (1.f - ig) * rg[c][v] + ig * h;
      new_hidden[ro + col] = nh;
      sC[wave][quad * 4 + v][col] = f2bf(nh);
    }
  }
  __syncthreads();
  // out MLP
  zero8(acc);
  wave_gemm(&sC[wave][0][0], 136, o1w, 128, 128, acc, lane);
  act_store<1>(acc, o1b, &sA[wave][0][0], 136, lane);
  __syncthreads();
  zero8(acc);
  wave_gemm(&sA[wave][0][0], 136, o2w, 128, 128, acc, lane);
  act_store<1>(acc, o2b, &sB[wave][0][0], 136, lane);
  __syncthreads();
  zero8(acc);
  wave_gemm(&sB[wave][0][0], 136, o3w, 128, 128, acc, lane);
#pragma unroll
  for (int v = 0; v < 4; ++v) {
    int r = row0 + quad * 4 + v;
    size_t ro = (size_t)r << 7;
#pragma unroll
    for (int c = 0; c < 8; ++c) {
      int col = c * 16 + m;
      pred[ro + col] = acc[c][v] + o3b[col];
    }
  }
}

// ---------------- host ----------------

extern "C" void kernel_launch(void* const* d_in, const int* in_sizes, int n_in,
                              void* d_out, int out_size, void* d_ws, size_t ws_size,
                              hipStream_t stream) {
  const float* inputs = (const float*)d_in[0];
  const float* edge_attr = (const float*)d_in[1];
  const int* send = (const int*)d_in[2];
  const int* recv = (const int*)d_in[3];
  const float* hidden = (const float*)d_in[4];
  const float* msg_b1 = (const float*)d_in[6];
  const float* msg_b2 = (const float*)d_in[8];
  const float* pm_b1 = (const float*)d_in[10];
  const float* pm_b2 = (const float*)d_in[12];
  const float* res_b1 = (const float*)d_in[14];
  const float* res_b2 = (const float*)d_in[16];
  const float* ir_b = (const float*)d_in[18];
  const float* ii_b = (const float*)d_in[20];
  const float* in_b = (const float*)d_in[22];
  const float* out_b1 = (const float*)d_in[27];
  const float* out_b2 = (const float*)d_in[29];
  const float* out_b3 = (const float*)d_in[31];

  char* ws = (char*)d_ws;
  size_t off = 0;
  auto alloc = [&](size_t bytes) {
    char* p = ws + off;
    off += (bytes + 255) & ~(size_t)255;
    return p;
  };
  float* hidden_sum = (float*)alloc((size_t)Bn * Nn * Hn * 4);   // 8 MB
  float* present_sum = (float*)alloc((size_t)Bn * Nn * Hn * 4);  // 8 MB
  float* cnt = (float*)alloc((size_t)Nn * 4);
  size_t zero_bytes = off;  // zero the three accumulators in one memset
  u16* hbf = (u16*)alloc((size_t)Bn * Nn * Hn * 2);
  u16* ibf = (u16*)alloc((size_t)Bn * Nn * Hn * 2);
  u16* w_msg1 = (u16*)alloc(128 * 256 * 2);
  u16* w_msg2 = (u16*)alloc(128 * 128 * 2);
  u16* w_pm1 = (u16*)alloc(128 * FPn * 2);
  u16* w_pm2 = (u16*)alloc(128 * 128 * 2);
  u16* w_res1 = (u16*)alloc(128 * 128 * 2);
  u16* w_res2 = (u16*)alloc(128 * 128 * 2);
  u16* w_ir = (u16*)alloc(128 * 128 * 2);
  u16* w_ii = (u16*)alloc(128 * 128 * 2);
  u16* w_in = (u16*)alloc(128 * 128 * 2);
  u16* w_hr = (u16*)alloc(128 * 128 * 2);
  u16* w_hi = (u16*)alloc(128 * 128 * 2);
  u16* w_hh = (u16*)alloc(128 * 128 * 2);
  u16* w_o1 = (u16*)alloc(128 * 128 * 2);
  u16* w_o2 = (u16*)alloc(128 * 128 * 2);
  u16* w_o3 = (u16*)alloc(128 * 128 * 2);

  hipMemsetAsync(d_ws, 0, zero_bytes, stream);

  WT wt;
  wt.d[0] = WD{(const float*)d_in[5], w_msg1, 256, 256};
  wt.d[1] = WD{(const float*)d_in[7], w_msg2, 128, 128};
  wt.d[2] = WD{(const float*)d_in[9], w_pm1, Fn, FPn};
  wt.d[3] = WD{(const float*)d_in[11], w_pm2, 128, 128};
  wt.d[4] = WD{(const float*)d_in[13], w_res1, 128, 128};
  wt.d[5] = WD{(const float*)d_in[15], w_res2, 128, 128};
  wt.d[6] = WD{(const float*)d_in[17], w_ir, 128, 128};
  wt.d[7] = WD{(const float*)d_in[19], w_ii, 128, 128};
  wt.d[8] = WD{(const float*)d_in[21], w_in, 128, 128};
  wt.d[9] = WD{(const float*)d_in[23], w_hr, 128, 128};
  wt.d[10] = WD{(const float*)d_in[25], w_hi, 128, 128};
  wt.d[11] = WD{(const float*)d_in[27 - 1], w_o1, 128, 128};  // d_in[26] out_w1
  wt.d[12] = WD{(const float*)d_in[28], w_o2, 128, 128};
  wt.d[13] = WD{(const float*)d_in[30], w_o3, 128, 128};
  wt.d[14] = WD{(const float*)d_in[25], w_hh, 128, 128};  // placeholder, fixed below
  wt.d[10] = WD{(const float*)d_in[24], w_hi, 128, 128};
  wt.d[14] = WD{(const float*)d_in[25], w_hh, 128, 128};

  wconv_kernel<<<15, 256, 0, stream>>>(wt);
  conv_kernel<<<(2 * Bn * Nn * Hn / 4) / 256, 256, 0, stream>>>(hidden, inputs, hbf, ibf);
  count_kernel<<<En / 256, 256, 0, stream>>>(recv, cnt);
  msg_kernel<<<(Bn * En) / 64, 256, 0, stream>>>(hbf, recv, send, w_msg1, msg_b1, w_msg2,
                                                 msg_b2, hidden_sum);
  pm_kernel<<<(Bn * En) / 64, 256, 0, stream>>>(edge_attr, recv, w_pm1, pm_b1, w_pm2, pm_b2,
                                                present_sum);
  float* pred = (float*)d_out;
  float* new_hidden = pred + (size_t)Bn * Nn * Hn;
  node_kernel<<<(Bn * Nn) / 64, 256, 0, stream>>>(
      ibf, hidden, hidden_sum, present_sum, cnt, w_res1, res_b1, w_res2, res_b2, w_ir, ir_b,
      w_ii, ii_b, w_in, in_b, w_hr, w_hi, w_hh, w_o1, out_b1, w_o2, out_b2, w_o3, out_b3,
      pred, new_hidden);
}